// Round 9
// baseline (54.937 us; speedup 1.0000x reference)
//
#include <hip/hip_runtime.h>
#include <cstddef>

// Problem constants
#define NB 4
#define LQ 512
#define LK 512
#define QF 256
#define NH 128
#define VD 256

__device__ __forceinline__ float fexp2(float x) {
    float r; asm("v_exp_f32 %0, %1" : "=v"(r) : "v"(x)); return r;
}
__device__ __forceinline__ float frcp(float x) {
    float r; asm("v_rcp_f32 %0, %1" : "=v"(r) : "v"(x)); return r;
}
__device__ __forceinline__ void fma4(float4& acc, float s, const float4 v) {
    acc.x = __builtin_fmaf(s, v.x, acc.x);
    acc.y = __builtin_fmaf(s, v.y, acc.y);
    acc.z = __builtin_fmaf(s, v.z, acc.z);
    acc.w = __builtin_fmaf(s, v.w, acc.w);
}

constexpr float kLog2e    = 1.4426950408889634f;
constexpr float kPreScale = 2.0f * kLog2e;   // tanh(x) = 1 - 2/(1 + exp2(kPreScale*x))

// ---------------------------------------------------------------------------
// K0: transpose W_q, W_k into f4-major float4 tiles (FROZEN).
// ---------------------------------------------------------------------------
__global__ __launch_bounds__(256) void transw_kernel(
    const float* __restrict__ W_q, const float* __restrict__ W_k,
    float4* __restrict__ wt)
{
    const int bid = blockIdx.x;          // 16 = 2 mats * 8 f4-groups
    const int mat = bid & 1;
    const int f4b = (bid >> 1) * 8;
    const float4* W4 = (const float4*)(mat ? W_k : W_q);
    float4* o = wt + (size_t)mat * 64 * NH;

    const int t  = threadIdx.x;
    const int h  = t & 127;
    const int fo = t >> 7;
    #pragma unroll
    for (int it = 0; it < 4; ++it) {
        const int f4 = f4b + fo + 2 * it;
        o[f4 * NH + h] = W4[h * 64 + f4];
    }
}

// ---------------------------------------------------------------------------
// K1: projections + exponentials (FROZEN).
//   eq  [row][h]             = exp2(ps * Q.Wq^T)   [2048][128]
//   ekt4[b][h4][j][c] (f32)  = exp2(ps * K.Wk^T), h=4*h4+c
// ---------------------------------------------------------------------------
__global__ __launch_bounds__(256) void proj_kernel(
    const float* __restrict__ queries, const float* __restrict__ keys,
    const float4* __restrict__ wt,
    float* __restrict__ eq, float* __restrict__ ekt4f)
{
    const int bid   = blockIdx.x;        // 512 = 2 which * 256 row-tiles(8)
    const int which = bid & 1;
    const int rt    = bid >> 1;
    const int row0  = rt * 8;
    const float4* In4 = (const float4*)(which ? keys : queries);
    const float4* w4  = wt + (size_t)which * 64 * NH;

    __shared__ float4 rows[8][64];       // 8KB

    const int t    = threadIdx.x;
    const int lane = t & 63;
    const int wid  = t >> 6;

    {   // stage 8 rows, coalesced
        const int f4 = t & 63;
        const int r  = t >> 6;
        rows[r][f4]     = In4[(size_t)(row0 + r) * 64 + f4];
        rows[r + 4][f4] = In4[(size_t)(row0 + r + 4) * 64 + f4];
    }
    __syncthreads();

    const int r0 = wid * 2;              // wave's 2 rows
    float acc[2][2] = {};
    #pragma unroll 4
    for (int f4 = 0; f4 < 64; ++f4) {
        const float4 w0 = w4[f4 * NH + lane];        // coalesced 1KB
        const float4 w1 = w4[f4 * NH + lane + 64];
        #pragma unroll
        for (int r = 0; r < 2; ++r) {
            const float4 x = rows[r0 + r][f4];       // wave-uniform broadcast
            acc[r][0] += w0.x * x.x + w0.y * x.y + w0.z * x.z + w0.w * x.w;
            acc[r][1] += w1.x * x.x + w1.y * x.y + w1.z * x.z + w1.w * x.w;
        }
    }

    if (which == 0) {
        #pragma unroll
        for (int r = 0; r < 2; ++r) {
            const size_t o = (size_t)(row0 + r0 + r) * NH;
            eq[o + lane]      = fexp2(kPreScale * acc[r][0]);
            eq[o + lane + 64] = fexp2(kPreScale * acc[r][1]);
        }
    } else {
        const int b  = row0 >> 9;
        const int j0 = (row0 & 511) + r0;
        #pragma unroll
        for (int r = 0; r < 2; ++r) {
            #pragma unroll
            for (int s = 0; s < 2; ++s) {
                const int h = lane + 64 * s;
                ekt4f[(((size_t)b * 32 + (h >> 2)) * LK + j0 + r) * 4 + (h & 3)]
                    = fexp2(kPreScale * acc[r][s]);
            }
        }
    }
}

// ---------------------------------------------------------------------------
// K2 (FUSED): scores + softmax-sum + attn write + PV + out, one kernel.
// SINGLE CHANGE vs R8: uniform full-LK compute — every chunk is computed
// unconditionally and masked AFTER (p=0 for j>=vl).  Scores at masked j are
// finite (|s| <= sum|W_v| -> p <= 1), so this is numerically safe.  Every
// block now has IDENTICAL cost regardless of valid_len -> the 512-block
// all-resident grid finishes in lockstep (R8 measured Occupancy 47%: CUs
// drawing small-vl blocks idled half the kernel).  ~2x wasted score VALU
// (~5us machine-integrated) buys back ~2x machine utilization (~20us).
// ---------------------------------------------------------------------------
__global__ __launch_bounds__(1024, 8) void fused_kernel(
    const float* __restrict__ eq, const float* __restrict__ ekt4f,
    const float* __restrict__ values, const int* __restrict__ valid_lens,
    const float* __restrict__ W_v,
    float* __restrict__ out, float* __restrict__ attn_out)
{
    const int id = blockIdx.x;           // 512 = 128 qt * 4 b (b fastest)
    const int b  = id & 3;
    const int i0 = (id >> 2) * 4;
    const int vl = valid_lens[b];

    __shared__ float  eq_lds[4][NH];
    __shared__ float  wv[NH];
    __shared__ float  attn_t[LK][4];     // [j][q], rows 16B-aligned
    __shared__ float4 pacc[8][4][VD / 4];
    __shared__ float  reds[16];

    const int t    = threadIdx.x;
    const int wid  = t >> 6;
    const int lane = t & 63;
    const int qi   = wid & 3;
    const int g    = wid >> 2;

    if (t < 4 * NH) ((float*)eq_lds)[t] = eq[(size_t)(b * LQ + i0) * NH + t];
    if (t < NH)     wv[t] = W_v[t];
    __syncthreads();

    const float4* q4  = (const float4*)eq_lds[qi];
    const float4* wv4 = (const float4*)wv;

    float sumA = 0.f, sumW = 0.f;
    #pragma unroll 8
    for (int h4 = 0; h4 < NH / 4; ++h4) {
        const float4 w = wv4[h4];
        sumW += (w.x + w.y) + (w.z + w.w);
        sumA += (fabsf(w.x) + fabsf(w.y)) + (fabsf(w.z) + fabsf(w.w));
    }

    // ---- Phase S: p for chunks {g, g+4} of query qi (unconditional) ----
    float p[2];
    float sum = 0.f;
    #pragma unroll
    for (int u = 0; u < 2; ++u) {
        const int jj = g + 4 * u;
        const int j  = jj * 64 + lane;
        const float4* pk4 = (const float4*)ekt4f + (size_t)b * 32 * LK + j;
        float a0 = 0.f, a1 = 0.f, a2 = 0.f, a3 = 0.f;
        #pragma unroll 4
        for (int h4 = 0; h4 < NH / 4; ++h4) {
            const float4 e = pk4[(size_t)h4 * LK];   // 16B/lane, 1KB/wave
            const float4 w = wv4[h4];
            const float4 q = q4[h4];
            a0 = __builtin_fmaf(w.x, frcp(__builtin_fmaf(q.x, e.x, 1.f)), a0);
            a1 = __builtin_fmaf(w.y, frcp(__builtin_fmaf(q.y, e.y, 1.f)), a1);
            a2 = __builtin_fmaf(w.z, frcp(__builtin_fmaf(q.z, e.z, 1.f)), a2);
            a3 = __builtin_fmaf(w.w, frcp(__builtin_fmaf(q.w, e.w, 1.f)), a3);
        }
        const float s = __builtin_fmaf(-2.f, (a0 + a1) + (a2 + a3), sumW);
        float pv = fexp2((s - sumA) * kLog2e);
        if (j >= vl) pv = 0.f;           // mask AFTER compute (uniform cost)
        p[u] = pv;
        sum += pv;
    }

    // ---- normalize: per-query sum across 4 g-waves ----
    #pragma unroll
    for (int off = 1; off < 64; off <<= 1)
        sum += __shfl_xor(sum, off, 64);
    if (lane == 0) reds[wid] = sum;
    __syncthreads();
    const float rs = frcp((reds[qi] + reds[qi + 4]) + (reds[qi + 8] + reds[qi + 12]));

    float* arow = attn_out + (size_t)(b * LQ + i0 + qi) * LK;
    #pragma unroll
    for (int u = 0; u < 2; ++u) {
        const int j = (g + 4 * u) * 64 + lane;
        const float a = p[u] * rs;
        arow[j]       = a;               // coalesced; zeros beyond vl
        attn_t[j][qi] = a;
    }
    __syncthreads();

    // ---- Phase PV: full 32-j strip (masked attn entries are 0) ----
    const int j0 = wid * 32;
    float4 acc4[4];
    #pragma unroll
    for (int q = 0; q < 4; ++q) acc4[q] = float4{0.f, 0.f, 0.f, 0.f};

    const float4* v4 = (const float4*)(values + (size_t)b * LK * VD);
    #pragma unroll 4
    for (int j = j0; j < j0 + 32; ++j) {
        const float4 a  = *(const float4*)&attn_t[j][0];   // all 4 q (uniform)
        const float4 vv = v4[(size_t)j * 64 + lane];       // coalesced 1KB
        fma4(acc4[0], a.x, vv);
        fma4(acc4[1], a.y, vv);
        fma4(acc4[2], a.z, vv);
        fma4(acc4[3], a.w, vv);
    }

    if (wid < 8) {
        #pragma unroll
        for (int q = 0; q < 4; ++q) pacc[wid][q][lane] = acc4[q];
    }
    __syncthreads();
    if (wid >= 8) {
        #pragma unroll
        for (int q = 0; q < 4; ++q) {
            const float4 pv = pacc[wid - 8][q][lane];
            pacc[wid - 8][q][lane] =
                float4{pv.x + acc4[q].x, pv.y + acc4[q].y,
                       pv.z + acc4[q].z, pv.w + acc4[q].w};
        }
    }
    __syncthreads();

    {   // final reduce: thread -> (q = t>>8, c = t&255)
        const int q = t >> 8;
        const int c = t & 255;
        float s = 0.f;
        #pragma unroll
        for (int k = 0; k < 8; ++k)
            s += ((const float*)&pacc[k][q][0])[c];
        out[(size_t)(b * LQ + i0 + q) * VD + c] = s;
    }
}

// ---------------------------------------------------------------------------
extern "C" void kernel_launch(void* const* d_in, const int* in_sizes, int n_in,
                              void* d_out, int out_size, void* d_ws, size_t ws_size,
                              hipStream_t stream)
{
    const float* queries    = (const float*)d_in[0];
    const float* keys       = (const float*)d_in[1];
    const float* values     = (const float*)d_in[2];
    const int*   valid_lens = (const int*)  d_in[3];
    const float* W_q        = (const float*)d_in[4];
    const float* W_k        = (const float*)d_in[5];
    const float* W_v        = (const float*)d_in[6];

    float* out      = (float*)d_out;                       // [NB, LQ, VD]
    float* attn_out = out + (size_t)NB * LQ * VD;          // [NB, LQ, LK]

    float*  eq    = (float*)d_ws;                          // [2048][128]  1MB
    float*  ekt4f = eq + (size_t)NB * LQ * NH;             // [4][32][512][4] 1MB
    float4* wt    = (float4*)(ekt4f + (size_t)NB * NH * LK); // [2][64][128] 256KB

    transw_kernel<<<16,  256,  0, stream>>>(W_q, W_k, wt);
    proj_kernel  <<<512, 256,  0, stream>>>(queries, keys, wt, eq, ekt4f);
    fused_kernel <<<512, 1024, 0, stream>>>(eq, ekt4f, values, valid_lens, W_v,
                                            out, attn_out);
}